// Round 3
// baseline (1917.915 us; speedup 1.0000x reference)
//
#include <hip/hip_runtime.h>
#include <stdint.h>

#define S_DIM 32
#define B_DIM 64
#define N_DIM 2048
#define F_DIM 16
#define E_DIM 32768
#define H_DIM 512
#define H3 1536
#define SB 2048
#define EPS_BN 1e-5f

typedef __attribute__((ext_vector_type(4))) float f32x4;
typedef __attribute__((ext_vector_type(8))) __bf16 bf16x8;

static __device__ __forceinline__ unsigned short f2bf(float f) {
    union { float f; unsigned int u; } v; v.f = f;
    unsigned int r = v.u + 0x7FFFu + ((v.u >> 16) & 1u);
    return (unsigned short)(r >> 16);
}

// ---------------- GCN stage 1: z[n][sb] = dot(x[sb,n,:], W1) ----------------
__global__ __launch_bounds__(256) void k_gcn1_dot(const float* __restrict__ x,
        const float* __restrict__ W1, float* __restrict__ z) {
    __shared__ float tile[64][65];
    int bn = blockIdx.x & 31;          // n tile (32)
    int bs = blockIdx.x >> 5;          // sb tile (32)
    int n0 = bn * 64, sb0 = bs * 64;
    float4 w0 = *(const float4*)&W1[0];
    float4 w1 = *(const float4*)&W1[4];
    float4 w2 = *(const float4*)&W1[8];
    float4 w3 = *(const float4*)&W1[12];
    int t = threadIdx.x;
    for (int i = 0; i < 16; ++i) {
        int idx = t + 256 * i;
        int nl = idx & 63, sl = idx >> 6;
        const float4* xv = (const float4*)(x + ((size_t)(sb0 + sl) * N_DIM + (n0 + nl)) * F_DIM);
        float4 a = xv[0], b = xv[1], c = xv[2], d = xv[3];
        float acc = a.x*w0.x + a.y*w0.y + a.z*w0.z + a.w*w0.w
                  + b.x*w1.x + b.y*w1.y + b.z*w1.z + b.w*w1.w
                  + c.x*w2.x + c.y*w2.y + c.z*w2.z + c.w*w2.w
                  + d.x*w3.x + d.y*w3.y + d.z*w3.z + d.w*w3.w;
        tile[nl][sl] = acc;
    }
    __syncthreads();
    for (int i = 0; i < 16; ++i) {
        int idx = t + 256 * i;
        int sl = idx & 63, nl = idx >> 6;
        z[(size_t)(n0 + nl) * SB + sb0 + sl] = tile[nl][sl];
    }
}

// ---------------- CSR build (edge_index is int32 per harness contract) ----------------
__global__ void k_degcnt(const int* __restrict__ ei, int* __restrict__ cnt) {
    int e = blockIdx.x * 256 + threadIdx.x;
    if (e < E_DIM) atomicAdd(&cnt[ei[E_DIM + e]], 1);
}
__global__ void k_dinv(const int* __restrict__ cnt, float* __restrict__ dinv) {
    int n = blockIdx.x * 256 + threadIdx.x;
    if (n < N_DIM) dinv[n] = rsqrtf(1.0f + (float)cnt[n]);
}
__global__ void k_scan(const int* __restrict__ cnt, int* __restrict__ rowptr) {
    __shared__ int sc[2048];
    int t = threadIdx.x;
    sc[t] = cnt[t]; sc[t + 1024] = cnt[t + 1024];
    __syncthreads();
    for (int off = 1; off < 2048; off <<= 1) {
        int a = (t >= off) ? sc[t - off] : 0;
        int b = (t + 1024 >= off) ? sc[t + 1024 - off] : 0;
        __syncthreads();
        sc[t] += a; sc[t + 1024] += b;
        __syncthreads();
    }
    rowptr[t] = sc[t] - cnt[t];
    rowptr[t + 1024] = sc[t + 1024] - cnt[t + 1024];
    if (t == 0) rowptr[2048] = E_DIM;
}
__global__ void k_fill(const int* __restrict__ ei, const int* __restrict__ rowptr,
                       int* __restrict__ cursor, int* __restrict__ cols) {
    int e = blockIdx.x * 256 + threadIdx.x;
    if (e < E_DIM) {
        int d = ei[E_DIM + e];
        int pos = atomicAdd(&cursor[d], 1);
        cols[rowptr[d] + pos] = ei[e];
    }
}

// ---------------- SpMM (gather, no atomics). mode0: sigmoid(acc+b1). mode1: BN(w2*acc+b2) ----------------
__global__ __launch_bounds__(256) void k_spmm(const float* __restrict__ in,
        float* __restrict__ outp, const int* __restrict__ rowptr, const int* __restrict__ cols,
        const float* __restrict__ dinv, int mode,
        const float* __restrict__ bp, const float* __restrict__ w2p,
        const float* __restrict__ gamma, const float* __restrict__ beta,
        const float* __restrict__ rmean, const float* __restrict__ rvar) {
    int n = blockIdx.x & 2047;
    int sb = ((blockIdx.x >> 11) << 8) + threadIdx.x;
    float dn = dinv[n];
    float acc = dn * dn * in[(size_t)n * SB + sb];   // self loop
    int i0 = rowptr[n], i1 = rowptr[n + 1];
    for (int idx = i0; idx < i1; ++idx) {
        int s = cols[idx];
        acc += dn * dinv[s] * in[(size_t)s * SB + sb];
    }
    float v;
    if (mode == 0) {
        v = acc + bp[0];
        v = 1.0f / (1.0f + __expf(-v));
    } else {
        v = w2p[0] * acc + bp[0];
        v = (v - rmean[n]) * rsqrtf(rvar[n] + EPS_BN) * gamma[n] + beta[n];
    }
    outp[(size_t)n * SB + sb] = v;
}

// ---------------- transpose + fp32->bf16: in (R,C) f32 -> out (C,R) bf16 ----------------
__global__ __launch_bounds__(256) void k_transpose_cvt(const float* __restrict__ in,
        unsigned short* __restrict__ outp, int R, int C) {
    __shared__ float tile[64][65];
    int nrt = R >> 6;
    int rt = blockIdx.x % nrt;
    int ct = blockIdx.x / nrt;
    int r0 = rt * 64, c0 = ct * 64;
    int t = threadIdx.x;
    for (int i = 0; i < 16; ++i) {
        int idx = t + i * 256;
        int cl = idx & 63, rl = idx >> 6;
        tile[rl][cl] = in[(size_t)(r0 + rl) * C + c0 + cl];
    }
    __syncthreads();
    for (int i = 0; i < 16; ++i) {
        int idx = t + i * 256;
        int rl = idx & 63, cl = idx >> 6;
        outp[(size_t)(c0 + cl) * R + r0 + rl] = f2bf(tile[rl][cl]);
    }
}

// ---------------- elementwise fp32 -> bf16 ----------------
__global__ void k_cvt_bf16(const float* __restrict__ in, unsigned short* __restrict__ outp, int nelem) {
    int i = (blockIdx.x * 256 + threadIdx.x) * 4;
    if (i < nelem) {
        float4 v = *(const float4*)&in[i];
        ushort4 o;
        o.x = f2bf(v.x); o.y = f2bf(v.y); o.z = f2bf(v.z); o.w = f2bf(v.w);
        *(ushort4*)&outp[i] = o;
    }
}

// ---------------- bf16 MFMA GEMM: C(M,N) = A(M,K) * B(N,K)^T + bias(N) ----------------
#define BM 128
#define BN 128
#define BKK 32
#define LDT 40

__global__ __launch_bounds__(256) void k_gemm_bf16(
        const unsigned short* __restrict__ A,
        const unsigned short* __restrict__ Bm,
        const float* __restrict__ bias,
        float* __restrict__ Cm, int M, int N, int K) {
    __shared__ __align__(16) unsigned short lA[BM * LDT];
    __shared__ __align__(16) unsigned short lB[BN * LDT];
    int mtiles = M / BM;
    int mt = blockIdx.x % mtiles;
    int nt = blockIdx.x / mtiles;
    int m0 = mt * BM, n0 = nt * BN;
    int t = threadIdx.x;
    int wave = t >> 6, lane = t & 63;
    int wm = (wave >> 1) * 64, wn = (wave & 1) * 64;
    int lrow = lane & 15, lk = (lane >> 4) * 8;
    int srow = t >> 1, scol = (t & 1) * 16;
    f32x4 acc[4][4] = {};
    for (int k0 = 0; k0 < K; k0 += BKK) {
        const unsigned short* ga = A  + (size_t)(m0 + srow) * K + k0 + scol;
        const unsigned short* gb = Bm + (size_t)(n0 + srow) * K + k0 + scol;
        *(uint4*)&lA[srow * LDT + scol]     = *(const uint4*)ga;
        *(uint4*)&lA[srow * LDT + scol + 8] = *(const uint4*)(ga + 8);
        *(uint4*)&lB[srow * LDT + scol]     = *(const uint4*)gb;
        *(uint4*)&lB[srow * LDT + scol + 8] = *(const uint4*)(gb + 8);
        __syncthreads();
        bf16x8 af[4], bg[4];
        #pragma unroll
        for (int i = 0; i < 4; ++i) {
            af[i] = *(const bf16x8*)&lA[(wm + i * 16 + lrow) * LDT + lk];
            bg[i] = *(const bf16x8*)&lB[(wn + i * 16 + lrow) * LDT + lk];
        }
        #pragma unroll
        for (int i = 0; i < 4; ++i)
            #pragma unroll
            for (int j = 0; j < 4; ++j)
                acc[i][j] = __builtin_amdgcn_mfma_f32_16x16x32_bf16(af[i], bg[j], acc[i][j], 0, 0, 0);
        __syncthreads();
    }
    int crow = (lane >> 4) * 4, ccol = lane & 15;
    #pragma unroll
    for (int i = 0; i < 4; ++i)
        #pragma unroll
        for (int j = 0; j < 4; ++j) {
            int gn = n0 + wn + j * 16 + ccol;
            float bv = bias[gn];
            #pragma unroll
            for (int r = 0; r < 4; ++r) {
                int gm = m0 + wm + i * 16 + crow + r;
                Cm[(size_t)gm * N + gn] = acc[i][j][r] + bv;
            }
        }
}

// ---------------- one GRU time step (fused ghat GEMM + gates) ----------------
__global__ __launch_bounds__(256) void k_gru_step(
        const float* __restrict__ gi,     // (B, 3H) for this t (bih already added)
        const float* __restrict__ Whh,    // (3H, H)
        const float* __restrict__ bhh,    // (3H)
        const float* __restrict__ hprev,  // (B, H)
        float* __restrict__ hnew,         // (B, H)
        float* __restrict__ yT,           // (H, S*B)
        float* __restrict__ hn_out,       // nullable: final-h output region
        int t_step) {
    int tid = threadIdx.x;
    int b = tid & 63;
    int i = tid >> 6;                 // 0..3
    int jh = blockIdx.x * 4 + i;      // 0..511
    __shared__ float lh[128 * 64];    // skewed [k][(b+k)&63]
    float accr = 0.f, accz = 0.f, accn = 0.f;
    for (int k0 = 0; k0 < H_DIM; k0 += 128) {
        for (int it = 0; it < 8; ++it) {
            int f = (tid + it * 256) * 4;
            int kk = f & 127, bb = f >> 7;
            float4 v = *(const float4*)&hprev[bb * H_DIM + k0 + kk];
            lh[(kk + 0) * 64 + ((bb + kk + 0) & 63)] = v.x;
            lh[(kk + 1) * 64 + ((bb + kk + 1) & 63)] = v.y;
            lh[(kk + 2) * 64 + ((bb + kk + 2) & 63)] = v.z;
            lh[(kk + 3) * 64 + ((bb + kk + 3) & 63)] = v.w;
        }
        __syncthreads();
        const float* wr = &Whh[(size_t)jh * H_DIM + k0];
        const float* wz = wr + (size_t)H_DIM * H_DIM;
        const float* wn = wz + (size_t)H_DIM * H_DIM;
        for (int kk = 0; kk < 128; kk += 4) {
            float4 vr = *(const float4*)&wr[kk];
            float4 vz = *(const float4*)&wz[kk];
            float4 vn = *(const float4*)&wn[kk];
            float h0 = lh[(kk + 0) * 64 + ((b + kk + 0) & 63)];
            float h1 = lh[(kk + 1) * 64 + ((b + kk + 1) & 63)];
            float h2 = lh[(kk + 2) * 64 + ((b + kk + 2) & 63)];
            float h3 = lh[(kk + 3) * 64 + ((b + kk + 3) & 63)];
            accr += h0 * vr.x + h1 * vr.y + h2 * vr.z + h3 * vr.w;
            accz += h0 * vz.x + h1 * vz.y + h2 * vz.z + h3 * vz.w;
            accn += h0 * vn.x + h1 * vn.y + h2 * vn.z + h3 * vn.w;
        }
        __syncthreads();
    }
    float hp = hprev[b * H_DIM + jh];
    float gr = gi[b * H3 + jh];
    float gz = gi[b * H3 + H_DIM + jh];
    float gn = gi[b * H3 + 2 * H_DIM + jh];
    float r = 1.0f / (1.0f + __expf(-(gr + accr + bhh[jh])));
    float z = 1.0f / (1.0f + __expf(-(gz + accz + bhh[H_DIM + jh])));
    float n = tanhf(gn + r * (accn + bhh[2 * H_DIM + jh]));
    float h = (1.0f - z) * n + z * hp;
    hnew[b * H_DIM + jh] = h;
    yT[(size_t)jh * SB + t_step * B_DIM + b] = h;
    if (hn_out) hn_out[b * H_DIM + jh] = h;
}

// ---------------- final linear: out[sb] = dot(y2[sb,:], Wlin) + blin ----------------
__global__ void k_final(const float* __restrict__ y2T, const float* __restrict__ Wlin,
                        const float* __restrict__ blin, float* __restrict__ outp) {
    int sb = blockIdx.x * 256 + threadIdx.x;
    float acc = blin[0];
    for (int k = 0; k < H_DIM; ++k)
        acc += y2T[(size_t)k * SB + sb] * Wlin[k];
    outp[sb] = acc;
}

extern "C" void kernel_launch(void* const* d_in, const int* in_sizes, int n_in,
                              void* d_out, int out_size, void* d_ws, size_t ws_size,
                              hipStream_t stream) {
    (void)in_sizes; (void)n_in; (void)out_size; (void)ws_size;
    const float*      x     = (const float*)d_in[0];
    const int*        ei    = (const int*)d_in[1];     // int inputs arrive as int32
    const float*      W1    = (const float*)d_in[2];
    const float*      b1    = (const float*)d_in[3];
    const float*      W2    = (const float*)d_in[4];
    const float*      b2    = (const float*)d_in[5];
    const float*      gamma = (const float*)d_in[6];
    const float*      beta  = (const float*)d_in[7];
    const float*      rmean = (const float*)d_in[8];
    const float*      rvar  = (const float*)d_in[9];
    const float*      Wih0  = (const float*)d_in[10];
    const float*      Whh0  = (const float*)d_in[11];
    const float*      bih0  = (const float*)d_in[12];
    const float*      bhh0  = (const float*)d_in[13];
    const float*      Wih1  = (const float*)d_in[14];
    const float*      Whh1  = (const float*)d_in[15];
    const float*      bih1  = (const float*)d_in[16];
    const float*      bhh1  = (const float*)d_in[17];
    const float*      Wlin  = (const float*)d_in[18];
    const float*      blin  = (const float*)d_in[19];
    float* outp = (float*)d_out;

    char* w = (char*)d_ws;
    auto alloc = [&](size_t bytes) { char* p = w; w += (bytes + 255) & ~(size_t)255; return p; };
    float*          zbuf   = (float*)alloc((size_t)N_DIM * SB * 4);        // z -> oT -> gi0
    float*          h1buf  = (float*)alloc((size_t)N_DIM * SB * 4);        // h1 -> o_bf16 -> gi1
    unsigned short* wih0b  = (unsigned short*)alloc((size_t)H3 * N_DIM * 2);
    unsigned short* wih1b  = (unsigned short*)alloc((size_t)H3 * H_DIM * 2);
    float*          y1T    = (float*)alloc((size_t)H_DIM * SB * 4);        // also y2T
    unsigned short* y1b    = (unsigned short*)alloc((size_t)SB * H_DIM * 2);
    float*          hA     = (float*)alloc(B_DIM * H_DIM * 4);
    float*          hB     = (float*)alloc(B_DIM * H_DIM * 4);
    float*          dinv   = (float*)alloc(N_DIM * 4);
    int*            degcnt = (int*)alloc(N_DIM * 4);
    int*            rowptr = (int*)alloc((N_DIM + 1) * 4);
    int*            cursor = (int*)alloc(N_DIM * 4);
    int*            cols   = (int*)alloc(E_DIM * 4);
    unsigned short* obf    = (unsigned short*)h1buf;

    hipMemsetAsync(degcnt, 0, N_DIM * 4, stream);
    hipMemsetAsync(cursor, 0, N_DIM * 4, stream);
    hipMemsetAsync(hA, 0, B_DIM * H_DIM * 4, stream);

    k_gcn1_dot<<<1024, 256, 0, stream>>>(x, W1, zbuf);
    k_degcnt<<<E_DIM / 256, 256, 0, stream>>>(ei, degcnt);
    k_dinv<<<N_DIM / 256, 256, 0, stream>>>(degcnt, dinv);
    k_scan<<<1, 1024, 0, stream>>>(degcnt, rowptr);
    k_fill<<<E_DIM / 256, 256, 0, stream>>>(ei, rowptr, cursor, cols);

    k_spmm<<<16384, 256, 0, stream>>>(zbuf, h1buf, rowptr, cols, dinv, 0, b1, (const float*)nullptr,
                                      gamma, beta, rmean, rvar);
    k_spmm<<<16384, 256, 0, stream>>>(h1buf, zbuf, rowptr, cols, dinv, 1, b2, W2,
                                      gamma, beta, rmean, rvar);
    // oT (N,SB) f32 -> o (SB,N) bf16
    k_transpose_cvt<<<(N_DIM / 64) * (SB / 64), 256, 0, stream>>>(zbuf, obf, N_DIM, SB);
    k_cvt_bf16<<<(H3 * N_DIM / 4) / 256, 256, 0, stream>>>(Wih0, wih0b, H3 * N_DIM);
    k_cvt_bf16<<<(H3 * H_DIM / 4) / 256, 256, 0, stream>>>(Wih1, wih1b, H3 * H_DIM);

    float* gi0 = zbuf;
    k_gemm_bf16<<<(SB / BM) * (H3 / BN), 256, 0, stream>>>(obf, wih0b, bih0, gi0, SB, H3, N_DIM);

    for (int t = 0; t < 32; ++t) {
        const float* hp = (t & 1) ? hB : hA;
        float* hn_ = (t & 1) ? hA : hB;
        float* hnout = (t == 31) ? (outp + 2048) : (float*)nullptr;
        k_gru_step<<<128, 256, 0, stream>>>(gi0 + (size_t)t * B_DIM * H3, Whh0, bhh0, hp, hn_, y1T, hnout, t);
    }
    // y1T (H, SB) f32 -> y1 (SB, H) bf16
    k_transpose_cvt<<<(H_DIM / 64) * (SB / 64), 256, 0, stream>>>(y1T, y1b, H_DIM, SB);
    float* gi1 = h1buf;
    k_gemm_bf16<<<(SB / BM) * (H3 / BN), 256, 0, stream>>>(y1b, wih1b, bih1, gi1, SB, H3, H_DIM);

    hipMemsetAsync(hA, 0, B_DIM * H_DIM * 4, stream);
    float* y2T = y1T;
    for (int t = 0; t < 32; ++t) {
        const float* hp = (t & 1) ? hB : hA;
        float* hn_ = (t & 1) ? hA : hB;
        float* hnout = (t == 31) ? (outp + 2048 + 32768) : (float*)nullptr;
        k_gru_step<<<128, 256, 0, stream>>>(gi1 + (size_t)t * B_DIM * H3, Whh1, bhh1, hp, hn_, y2T, hnout, t);
    }
    k_final<<<SB / 256, 256, 0, stream>>>(y2T, Wlin, blin, outp);
}